// Round 4
// baseline (512.417 us; speedup 1.0000x reference)
//
#include <hip/hip_runtime.h>

#define NN 50000
#define NE 200000
#define DD 384

typedef unsigned short u16;
typedef unsigned int   u32;
typedef __attribute__((ext_vector_type(8))) __bf16 bf16x8;
typedef __attribute__((ext_vector_type(8))) short  short8;
typedef __attribute__((ext_vector_type(4))) float  f32x4;

// ---------- bf16 helpers (raw ushort storage) ----------
__device__ __forceinline__ float bf2f(u16 v) {
    union { u32 u; float f; } x; x.u = ((u32)v) << 16; return x.f;
}
__device__ __forceinline__ u16 f2bf(float f) {
    union { float f; u32 u; } x; x.f = f;
    u32 r = x.u + 0x7fff + ((x.u >> 16) & 1);   // RNE
    return (u16)(r >> 16);
}

// ---------- input dtype detector: flag=1 -> inputs are fp32 ----------
// bf16 N(0,1) data: ~0 entries with exponent>=0x86 (|x|>=64).
// fp32 data read as u16: low halves are ~uniform bits -> ~48% qualify.
__global__ __launch_bounds__(256) void detect_k(const u16* __restrict__ p,
                                                int* __restrict__ flag) {
    __shared__ int tot;
    if (threadIdx.x == 0) tot = 0;
    __syncthreads();
    int bad = 0;
    for (int i = threadIdx.x; i < 8192; i += 256) {
        u16 v = p[i];
        int e = (v >> 7) & 0xFF;
        if (e >= 0x86) bad++;
    }
    atomicAdd(&tot, bad);
    __syncthreads();
    if (threadIdx.x == 0) flag[0] = (tot > 400) ? 1 : 0;
}

__device__ __forceinline__ float ldf(const void* p, size_t i, int dt) {
    return dt ? ((const float*)p)[i] : bf2f(((const u16*)p)[i]);
}

// ---------- weight pack: Wt[n][k] = W[k][n] bf16, n in [0,1536): Q|K|V|O ----
__global__ void packw_k(const void* __restrict__ WQ, const void* __restrict__ WK,
                        const void* __restrict__ WV, const void* __restrict__ WO,
                        u16* __restrict__ Wt, const int* __restrict__ dtf) {
    int idx = blockIdx.x * 256 + threadIdx.x;
    if (idx >= 1536 * 384) return;
    int dt = dtf[0];
    int n = idx / 384, k = idx - n * 384;
    const void* W; int c;
    if (n < 384)       { W = WQ; c = n; }
    else if (n < 768)  { W = WK; c = n - 384; }
    else if (n < 1152) { W = WV; c = n - 768; }
    else               { W = WO; c = n - 1152; }
    size_t off = (size_t)k * 384 + c;
    Wt[idx] = dt ? f2bf(((const float*)W)[off]) : ((const u16*)W)[off];
}

// ---------- CSR build ----------
__global__ void zero_k(int* p, int n) {
    int i = blockIdx.x * 256 + threadIdx.x;
    if (i < n) p[i] = 0;
}
__global__ void hist_k(const int* __restrict__ eidx, int* __restrict__ cnt) {
    int e = blockIdx.x * 256 + threadIdx.x;
    if (e < NE) {
        int d = eidx[NE + e];
        if ((u32)d < NN) atomicAdd(&cnt[d], 1);
    }
}
__global__ __launch_bounds__(256) void scan1_k(const int* __restrict__ cnt,
                                               int* __restrict__ indptr,
                                               int* __restrict__ bsum) {
    __shared__ int tmp[256];
    int i = blockIdx.x * 256 + threadIdx.x;
    int v = (i < NN) ? cnt[i] : 0;
    tmp[threadIdx.x] = v;
    __syncthreads();
    #pragma unroll
    for (int off = 1; off < 256; off <<= 1) {
        int t = tmp[threadIdx.x];
        int a = (threadIdx.x >= off) ? tmp[threadIdx.x - off] : 0;
        __syncthreads();
        tmp[threadIdx.x] = t + a;
        __syncthreads();
    }
    if (i < NN) indptr[i + 1] = tmp[threadIdx.x];
    if (threadIdx.x == 255) bsum[blockIdx.x] = tmp[255];
}
__global__ __launch_bounds__(256) void scan2_k(int* __restrict__ bsum, int nb) {
    __shared__ int tmp[256];
    int v = (threadIdx.x < nb) ? bsum[threadIdx.x] : 0;
    tmp[threadIdx.x] = v;
    __syncthreads();
    #pragma unroll
    for (int off = 1; off < 256; off <<= 1) {
        int t = tmp[threadIdx.x];
        int a = (threadIdx.x >= off) ? tmp[threadIdx.x - off] : 0;
        __syncthreads();
        tmp[threadIdx.x] = t + a;
        __syncthreads();
    }
    if (threadIdx.x < nb) bsum[threadIdx.x] = tmp[threadIdx.x] - v;  // exclusive
}
__global__ void scan3_k(int* __restrict__ indptr, const int* __restrict__ bsum,
                        int* __restrict__ cnt) {
    int i = blockIdx.x * 256 + threadIdx.x;
    if (i < NN) { indptr[i + 1] += bsum[blockIdx.x]; cnt[i] = 0; }
    if (i == 0) indptr[0] = 0;
}
__global__ void scatter_k(const int* __restrict__ eidx, const int* __restrict__ indptr,
                          int* __restrict__ cur, int* __restrict__ eids) {
    int e = blockIdx.x * 256 + threadIdx.x;
    if (e < NE) {
        int d = eidx[NE + e];
        if ((u32)d < NN) {
            int p = atomicAdd(&cur[d], 1);
            int slot = indptr[d] + p;
            if ((u32)slot < NE) eids[slot] = e;
        }
    }
}

// ---------- MFMA GEMM: C[M,*] = A[M,384] @ Bt[*,384]^T ----------
// 128x128 tile, 4 waves 2x2, each wave 4x4 frags of 16x16x32 bf16.
// AFLEX=1: A dtype per flag (fp32 or bf16). AFLEX=0: A is bf16 (internal).
// EPI=0: bf16 store at ldc. EPI=1: fp32 store + residual (dtype per flag).
template <int EPI, int AFLEX>
__global__ __launch_bounds__(256) void gemm_k(
    const void* __restrict__ A, const u16* __restrict__ Bt,
    u16* __restrict__ Cb, float* __restrict__ Cf,
    const void* __restrict__ resid, const int* __restrict__ dtf,
    int M, int ldc) {
    __shared__ __align__(16) short As[128 * 32];
    __shared__ __align__(16) short Bs[128 * 32];
    const int dt   = dtf[0];
    const int tid  = threadIdx.x;
    const int lane = tid & 63;
    const int wave = tid >> 6;
    const int m0 = blockIdx.x * 128;
    const int n0 = blockIdx.y * 128;
    const int wm = (wave >> 1) * 64;
    const int wn = (wave & 1) * 64;
    const int q = lane >> 4;     // 0..3
    const int r = lane & 15;     // 0..15

    f32x4 acc[4][4];
    #pragma unroll
    for (int i = 0; i < 4; i++)
        #pragma unroll
        for (int j = 0; j < 4; j++) acc[i][j] = (f32x4)(0.0f);

    const int srow = tid >> 2;          // 0..63
    const int scol = (tid & 3) * 8;     // element offset in 32-wide K block

    for (int kb = 0; kb < 12; ++kb) {
        const int k0 = kb * 32;
        #pragma unroll
        for (int h = 0; h < 2; ++h) {
            int row = h * 64 + srow;
            int am = m0 + row; am = am < M ? am : M - 1;
            short8 av;
            if (AFLEX && dt) {
                const float* ap = (const float*)A + (size_t)am * 384 + k0 + scol;
                f32x4 a0 = *(const f32x4*)ap;
                f32x4 a1 = *(const f32x4*)(ap + 4);
                av[0] = (short)f2bf(a0[0]); av[1] = (short)f2bf(a0[1]);
                av[2] = (short)f2bf(a0[2]); av[3] = (short)f2bf(a0[3]);
                av[4] = (short)f2bf(a1[0]); av[5] = (short)f2bf(a1[1]);
                av[6] = (short)f2bf(a1[2]); av[7] = (short)f2bf(a1[3]);
            } else {
                av = *(const short8*)((const u16*)A + (size_t)am * 384 + k0 + scol);
            }
            *(short8*)&As[row * 32 + scol] = av;
            short8 bv = *(const short8*)(Bt + (size_t)(n0 + row) * 384 + k0 + scol);
            *(short8*)&Bs[row * 32 + scol] = bv;
        }
        __syncthreads();
        bf16x8 af[4], bfr[4];
        #pragma unroll
        for (int i = 0; i < 4; i++)
            af[i] = *(const bf16x8*)&As[(wm + i * 16 + r) * 32 + q * 8];
        #pragma unroll
        for (int j = 0; j < 4; j++)
            bfr[j] = *(const bf16x8*)&Bs[(wn + j * 16 + r) * 32 + q * 8];
        #pragma unroll
        for (int i = 0; i < 4; i++)
            #pragma unroll
            for (int j = 0; j < 4; j++)
                acc[i][j] = __builtin_amdgcn_mfma_f32_16x16x32_bf16(
                    af[i], bfr[j], acc[i][j], 0, 0, 0);
        __syncthreads();
    }

    // D layout: col = lane&15, row = (lane>>4)*4 + reg   [measured m89/m91]
    #pragma unroll
    for (int i = 0; i < 4; i++) {
        #pragma unroll
        for (int rr = 0; rr < 4; ++rr) {
            int m = m0 + wm + i * 16 + q * 4 + rr;
            if (m >= M) continue;
            #pragma unroll
            for (int j = 0; j < 4; j++) {
                int n = n0 + wn + j * 16 + r;
                float v = acc[i][j][rr];
                if (EPI == 0) {
                    Cb[(size_t)m * ldc + n] = f2bf(v);
                } else {
                    Cf[(size_t)m * 384 + n] = v + ldf(resid, (size_t)m * 384 + n, dt);
                }
            }
        }
    }
}

// ---------- per-node attention ----------
// wave per node; lanes 0-31 = head0, 32-63 = head1; 6 elems/lane (192/32).
// q read from qbuf row into regs, agg written in-place over same row.
__global__ __launch_bounds__(256) void attn_k(
    u16* __restrict__ qbuf,              // [NN][384] bf16, becomes agg
    const u16* __restrict__ kv,          // [NN][768] bf16 = k|v
    const int* __restrict__ eidx,
    const void* __restrict__ eattr, const void* __restrict__ WE,
    const int* __restrict__ indptr, const int* __restrict__ eids,
    const int* __restrict__ dtf) {
    int node = blockIdx.x * 4 + (threadIdx.x >> 6);
    if (node >= NN) return;
    int dt = dtf[0];
    int lane = threadIdx.x & 63;
    int half = lane >> 5;
    int j = lane & 31;
    int col = half * 192 + j * 6;

    float qv[6], we[6];
    {
        const u32* p = (const u32*)(qbuf + (size_t)node * 384 + col);
        #pragma unroll
        for (int t = 0; t < 3; t++) {
            u32 w = p[t];
            qv[2 * t] = bf2f(w & 0xffff); qv[2 * t + 1] = bf2f(w >> 16);
        }
        #pragma unroll
        for (int t = 0; t < 6; t++) we[t] = ldf(WE, col + t, dt);
    }
    int beg = indptr[node], end = indptr[node + 1];
    if (beg < 0) beg = 0; if (beg > NE) beg = NE;
    if (end < beg) end = beg; if (end > NE) end = NE;
    float m_run = -1e30f, l_run = 0.0f;
    float acc[6] = {0, 0, 0, 0, 0, 0};

    for (int it = beg; it < end; ++it) {
        int eid = eids[it];
        if ((u32)eid >= NE) eid = 0;
        int src = eidx[eid];                    // row 0 = src
        if ((u32)src >= NN) src = 0;
        float attr = ldf(eattr, eid, dt);
        const u32* kp = (const u32*)(kv + (size_t)src * 768 + col);
        const u32* vp = (const u32*)(kv + (size_t)src * 768 + 384 + col);
        float kj[6], vj[6];
        #pragma unroll
        for (int t = 0; t < 3; t++) {
            u32 wk = kp[t];
            kj[2 * t]     = bf2f(wk & 0xffff) + attr * we[2 * t];
            kj[2 * t + 1] = bf2f(wk >> 16)    + attr * we[2 * t + 1];
            u32 wv = vp[t];
            vj[2 * t]     = bf2f(wv & 0xffff) + attr * we[2 * t];
            vj[2 * t + 1] = bf2f(wv >> 16)    + attr * we[2 * t + 1];
        }
        float part = qv[0] * kj[0] + qv[1] * kj[1] + qv[2] * kj[2] +
                     qv[3] * kj[3] + qv[4] * kj[4] + qv[5] * kj[5];
        #pragma unroll
        for (int off = 1; off < 32; off <<= 1) part += __shfl_xor(part, off, 64);
        float s = part * 0.07216878364870323f;   // 1/sqrt(192)
        float mn = fmaxf(m_run, s);
        float corr = __expf(m_run - mn);
        float p = __expf(s - mn);
        l_run = l_run * corr + p;
        #pragma unroll
        for (int t = 0; t < 6; t++) acc[t] = acc[t] * corr + p * vj[t];
        m_run = mn;
    }
    float inv = (end > beg) ? 1.0f / (l_run + 1e-16f) : 0.0f;
    u16* ar = qbuf + (size_t)node * 384 + col;   // in-place over q row
    #pragma unroll
    for (int t = 0; t < 6; t++) ar[t] = f2bf(acc[t] * inv);
}

// ---------- LayerNorm: wave per row; output dtype per flag ----------
__global__ __launch_bounds__(256) void ln_k(const float* __restrict__ x,
                                            const void* __restrict__ g,
                                            const void* __restrict__ b,
                                            void* __restrict__ out,
                                            const int* __restrict__ dtf) {
    int node = blockIdx.x * 4 + (threadIdx.x >> 6);
    if (node >= NN) return;
    int dt = dtf[0];
    int lane = threadIdx.x & 63;
    const float* row = x + (size_t)node * 384 + lane * 6;
    float v[6];
    #pragma unroll
    for (int t = 0; t < 6; t++) v[t] = row[t];
    float s = v[0] + v[1] + v[2] + v[3] + v[4] + v[5];
    #pragma unroll
    for (int off = 1; off < 64; off <<= 1) s += __shfl_xor(s, off, 64);
    float mean = s * (1.0f / 384.0f);
    float sq = 0.0f;
    #pragma unroll
    for (int t = 0; t < 6; t++) { float d = v[t] - mean; sq += d * d; }
    #pragma unroll
    for (int off = 1; off < 64; off <<= 1) sq += __shfl_xor(sq, off, 64);
    float rstd = rsqrtf(sq * (1.0f / 384.0f) + 1e-5f);
    size_t o0 = (size_t)node * 384 + lane * 6;
    #pragma unroll
    for (int t = 0; t < 6; t++) {
        float gv = ldf(g, lane * 6 + t, dt), bv = ldf(b, lane * 6 + t, dt);
        float val = (v[t] - mean) * rstd * gv + bv;
        if (dt) ((float*)out)[o0 + t] = val;
        else    ((u16*)out)[o0 + t] = f2bf(val);
    }
}

// ---------- launch ----------
extern "C" void kernel_launch(void* const* d_in, const int* in_sizes, int n_in,
                              void* d_out, int out_size, void* d_ws, size_t ws_size,
                              hipStream_t stream) {
    const void* emb   = d_in[0];
    const int*  eidx  = (const int*)d_in[1];
    const void* eattr = d_in[2];
    const void* WQ    = d_in[3];
    const void* WK    = d_in[4];
    const void* WV    = d_in[5];
    const void* WE    = d_in[6];
    const void* WO    = d_in[7];
    const void* lng   = d_in[8];
    const void* lnb   = d_in[9];

    char* ws = (char*)d_ws;
    // Layout: 79,180,800 bytes total. q/agg live in d_out's first 38.4 MB.
    const size_t OFF_IPTR = 0;           // (NN+1)*4 -> pad 200,064
    const size_t OFF_CNT  = 200064;      // NN*4 -> 400,064
    const size_t OFF_BSUM = 400064;      // 256*4 -> 401,088
    const size_t OFF_FLAG = 401088;      // 64 -> 401,152
    const size_t OFF_EIDS = 401152;      // NE*4 -> 1,201,152
    const size_t OFF_WT   = 1201152;     // 1536*384*2 -> 2,380,800
    const size_t OFF_KV   = 2380800;     // 50000*768*2 -> 79,180,800
                                         // fp32 pre-LN (76,800,000) aliases KV

    if (ws_size < 79180800) return;      // diagnostic: absmax 5.34 => ws too small

    int*   indptr = (int*)(ws + OFF_IPTR);
    int*   cnt    = (int*)(ws + OFF_CNT);
    int*   bsum   = (int*)(ws + OFF_BSUM);
    int*   dtf    = (int*)(ws + OFF_FLAG);
    int*   eids   = (int*)(ws + OFF_EIDS);
    u16*   Wt     = (u16*)(ws + OFF_WT);
    u16*   kv     = (u16*)(ws + OFF_KV);
    float* outp   = (float*)(ws + OFF_KV);    // aliases kv after attn
    u16*   qa     = (u16*)d_out;              // q -> agg scratch (bf16 u16)

    const int NB_N = (NN + 255) / 256;   // 196
    const int NB_E = (NE + 255) / 256;   // 782

    detect_k<<<1, 256, 0, stream>>>((const u16*)emb, dtf);
    packw_k<<<(1536 * 384 + 255) / 256, 256, 0, stream>>>(WQ, WK, WV, WO, Wt, dtf);
    zero_k<<<NB_N, 256, 0, stream>>>(cnt, NN);
    hist_k<<<NB_E, 256, 0, stream>>>(eidx, cnt);
    scan1_k<<<NB_N, 256, 0, stream>>>(cnt, indptr, bsum);
    scan2_k<<<1, 256, 0, stream>>>(bsum, NB_N);
    scan3_k<<<NB_N, 256, 0, stream>>>(indptr, bsum, cnt);
    scatter_k<<<NB_E, 256, 0, stream>>>(eidx, indptr, cnt, eids);

    // q projection -> d_out (bf16)
    gemm_k<0, 1><<<dim3(391, 3), 256, 0, stream>>>(emb, Wt, qa, nullptr, nullptr, dtf, NN, 384);
    // k|v projection -> kv (bf16, ld 768)
    gemm_k<0, 1><<<dim3(391, 6), 256, 0, stream>>>(emb, Wt + 384 * 384, kv, nullptr, nullptr, dtf, NN, 768);

    attn_k<<<(NN + 3) / 4, 256, 0, stream>>>(qa, kv, eidx, eattr, WE, indptr, eids, dtf);

    // output projection + residual -> fp32 outp (over kv)
    gemm_k<1, 0><<<dim3(391, 3), 256, 0, stream>>>(qa, Wt + 1152 * 384, nullptr, outp, emb, dtf, NN, 384);

    ln_k<<<(NN + 3) / 4, 256, 0, stream>>>(outp, lng, lnb, d_out, dtf);
}

// Round 5
// 505.966 us; speedup vs baseline: 1.0128x; 1.0128x over previous
//
#include <hip/hip_runtime.h>

#define NN 50000
#define NE 200000
#define DD 384

typedef unsigned short u16;
typedef unsigned int   u32;
typedef __attribute__((ext_vector_type(8))) __bf16 bf16x8;
typedef __attribute__((ext_vector_type(8))) short  short8;
typedef __attribute__((ext_vector_type(4))) float  f32x4;

// ---------- bf16 helpers (raw ushort storage) ----------
__device__ __forceinline__ float bf2f(u16 v) {
    union { u32 u; float f; } x; x.u = ((u32)v) << 16; return x.f;
}
__device__ __forceinline__ u16 f2bf(float f) {
    union { float f; u32 u; } x; x.f = f;
    u32 r = x.u + 0x7fff + ((x.u >> 16) & 1);   // RNE
    return (u16)(r >> 16);
}

// ---------- input dtype detector: flag=1 -> inputs are fp32 ----------
__global__ __launch_bounds__(256) void detect_k(const u16* __restrict__ p,
                                                int* __restrict__ flag) {
    __shared__ int tot;
    if (threadIdx.x == 0) tot = 0;
    __syncthreads();
    int bad = 0;
    for (int i = threadIdx.x; i < 8192; i += 256) {
        u16 v = p[i];
        int e = (v >> 7) & 0xFF;
        if (e >= 0x86) bad++;
    }
    atomicAdd(&tot, bad);
    __syncthreads();
    if (threadIdx.x == 0) flag[0] = (tot > 400) ? 1 : 0;
}

__device__ __forceinline__ float ldf(const void* p, size_t i, int dt) {
    return dt ? ((const float*)p)[i] : bf2f(((const u16*)p)[i]);
}

// ---------- weight pack: Wt[n][k] = W[k][n] bf16, n in [0,1536): Q|K|V|O ----
__global__ void packw_k(const void* __restrict__ WQ, const void* __restrict__ WK,
                        const void* __restrict__ WV, const void* __restrict__ WO,
                        u16* __restrict__ Wt, const int* __restrict__ dtf) {
    int idx = blockIdx.x * 256 + threadIdx.x;
    if (idx >= 1536 * 384) return;
    int dt = dtf[0];
    int n = idx / 384, k = idx - n * 384;
    const void* W; int c;
    if (n < 384)       { W = WQ; c = n; }
    else if (n < 768)  { W = WK; c = n - 384; }
    else if (n < 1152) { W = WV; c = n - 768; }
    else               { W = WO; c = n - 1152; }
    size_t off = (size_t)k * 384 + c;
    Wt[idx] = dt ? f2bf(((const float*)W)[off]) : ((const u16*)W)[off];
}

// ---------- CSR build ----------
__global__ void zero_k(int* p, int n) {
    int i = blockIdx.x * 256 + threadIdx.x;
    if (i < n) p[i] = 0;
}
__global__ void hist_k(const int* __restrict__ eidx, int* __restrict__ cnt) {
    int e = blockIdx.x * 256 + threadIdx.x;
    if (e < NE) {
        int d = eidx[NE + e];
        if ((u32)d < NN) atomicAdd(&cnt[d], 1);
    }
}
__global__ __launch_bounds__(256) void scan1_k(const int* __restrict__ cnt,
                                               int* __restrict__ indptr,
                                               int* __restrict__ bsum) {
    __shared__ int tmp[256];
    int i = blockIdx.x * 256 + threadIdx.x;
    int v = (i < NN) ? cnt[i] : 0;
    tmp[threadIdx.x] = v;
    __syncthreads();
    #pragma unroll
    for (int off = 1; off < 256; off <<= 1) {
        int t = tmp[threadIdx.x];
        int a = (threadIdx.x >= off) ? tmp[threadIdx.x - off] : 0;
        __syncthreads();
        tmp[threadIdx.x] = t + a;
        __syncthreads();
    }
    if (i < NN) indptr[i + 1] = tmp[threadIdx.x];
    if (threadIdx.x == 255) bsum[blockIdx.x] = tmp[255];
}
__global__ __launch_bounds__(256) void scan2_k(int* __restrict__ bsum, int nb) {
    __shared__ int tmp[256];
    int v = (threadIdx.x < nb) ? bsum[threadIdx.x] : 0;
    tmp[threadIdx.x] = v;
    __syncthreads();
    #pragma unroll
    for (int off = 1; off < 256; off <<= 1) {
        int t = tmp[threadIdx.x];
        int a = (threadIdx.x >= off) ? tmp[threadIdx.x - off] : 0;
        __syncthreads();
        tmp[threadIdx.x] = t + a;
        __syncthreads();
    }
    if (threadIdx.x < nb) bsum[threadIdx.x] = tmp[threadIdx.x] - v;  // exclusive
}
__global__ void scan3_k(int* __restrict__ indptr, const int* __restrict__ bsum,
                        int* __restrict__ cnt) {
    int i = blockIdx.x * 256 + threadIdx.x;
    if (i < NN) { indptr[i + 1] += bsum[blockIdx.x]; cnt[i] = 0; }
    if (i == 0) indptr[0] = 0;
}
__global__ void scatter_k(const int* __restrict__ eidx, const int* __restrict__ indptr,
                          int* __restrict__ cur, int* __restrict__ eids) {
    int e = blockIdx.x * 256 + threadIdx.x;
    if (e < NE) {
        int d = eidx[NE + e];
        if ((u32)d < NN) {
            int p = atomicAdd(&cur[d], 1);
            int slot = indptr[d] + p;
            if ((u32)slot < NE) eids[slot] = e;
        }
    }
}

// ---------- MFMA GEMM, n-fast grid: blockIdx.x = n-tile, blockIdx.y = m-tile.
// 128x128 tile, 4 waves 2x2, 4x4 frags of 16x16x32 bf16.
// MODE 0 (QKV): A per dt flag; n<384 -> q (ld 384), n>=384 -> kv (ld 768).
// MODE 1 (OUT): A bf16; C = bf16 preln = acc + resid (resid dtype per flag).
template <int MODE>
__global__ __launch_bounds__(256) void gemm_k(
    const void* __restrict__ A, const u16* __restrict__ Bt,
    u16* __restrict__ qd, u16* __restrict__ kvd, u16* __restrict__ preln,
    const void* __restrict__ resid, const int* __restrict__ dtf, int M) {
    __shared__ __align__(16) short As[128 * 32];
    __shared__ __align__(16) short Bs[128 * 32];
    const int dt   = dtf[0];
    const int tid  = threadIdx.x;
    const int lane = tid & 63;
    const int wave = tid >> 6;
    const int n0 = blockIdx.x * 128;
    const int m0 = blockIdx.y * 128;
    const int wm = (wave >> 1) * 64;
    const int wn = (wave & 1) * 64;
    const int q = lane >> 4;     // 0..3
    const int r = lane & 15;     // 0..15

    f32x4 acc[4][4];
    #pragma unroll
    for (int i = 0; i < 4; i++)
        #pragma unroll
        for (int j = 0; j < 4; j++) acc[i][j] = (f32x4)(0.0f);

    const int srow = tid >> 2;          // 0..63
    const int scol = (tid & 3) * 8;     // element offset in 32-wide K block

    for (int kb = 0; kb < 12; ++kb) {
        const int k0 = kb * 32;
        #pragma unroll
        for (int h = 0; h < 2; ++h) {
            int row = h * 64 + srow;
            int am = m0 + row; am = am < M ? am : M - 1;
            short8 av;
            if (MODE == 0 && dt) {
                const float* ap = (const float*)A + (size_t)am * 384 + k0 + scol;
                f32x4 a0 = *(const f32x4*)ap;
                f32x4 a1 = *(const f32x4*)(ap + 4);
                av[0] = (short)f2bf(a0[0]); av[1] = (short)f2bf(a0[1]);
                av[2] = (short)f2bf(a0[2]); av[3] = (short)f2bf(a0[3]);
                av[4] = (short)f2bf(a1[0]); av[5] = (short)f2bf(a1[1]);
                av[6] = (short)f2bf(a1[2]); av[7] = (short)f2bf(a1[3]);
            } else {
                av = *(const short8*)((const u16*)A + (size_t)am * 384 + k0 + scol);
            }
            *(short8*)&As[row * 32 + scol] = av;
            short8 bv = *(const short8*)(Bt + (size_t)(n0 + row) * 384 + k0 + scol);
            *(short8*)&Bs[row * 32 + scol] = bv;
        }
        __syncthreads();
        bf16x8 af[4], bfr[4];
        #pragma unroll
        for (int i = 0; i < 4; i++)
            af[i] = *(const bf16x8*)&As[(wm + i * 16 + r) * 32 + q * 8];
        #pragma unroll
        for (int j = 0; j < 4; j++)
            bfr[j] = *(const bf16x8*)&Bs[(wn + j * 16 + r) * 32 + q * 8];
        #pragma unroll
        for (int i = 0; i < 4; i++)
            #pragma unroll
            for (int j = 0; j < 4; j++)
                acc[i][j] = __builtin_amdgcn_mfma_f32_16x16x32_bf16(
                    af[i], bfr[j], acc[i][j], 0, 0, 0);
        __syncthreads();
    }

    // block-uniform destination routing
    u16* C; int ld, c0;
    if (MODE == 0) {
        if (n0 < 384) { C = qd;  ld = 384; c0 = n0; }
        else          { C = kvd; ld = 768; c0 = n0 - 384; }
    } else {
        C = preln; ld = 384; c0 = n0;
    }

    // D layout: col = lane&15, row = (lane>>4)*4 + reg   [measured m89/m91]
    #pragma unroll
    for (int i = 0; i < 4; i++) {
        #pragma unroll
        for (int rr = 0; rr < 4; ++rr) {
            int m = m0 + wm + i * 16 + q * 4 + rr;
            if (m >= M) continue;
            #pragma unroll
            for (int j = 0; j < 4; j++) {
                int n = c0 + wn + j * 16 + r;
                float v = acc[i][j][rr];
                if (MODE == 1)
                    v += ldf(resid, (size_t)m * 384 + n, dt);
                C[(size_t)m * ld + n] = f2bf(v);
            }
        }
    }
}

// ---------- per-node attention ----------
// wave per node; lanes 0-31 = head0, 32-63 = head1; 6 elems/lane (192/32).
// q read from qbuf row into regs, agg written in-place over same row.
__global__ __launch_bounds__(256) void attn_k(
    u16* __restrict__ qbuf,              // [NN][384] bf16, becomes agg
    const u16* __restrict__ kv,          // [NN][768] bf16 = k|v
    const int* __restrict__ eidx,
    const void* __restrict__ eattr, const void* __restrict__ WE,
    const int* __restrict__ indptr, const int* __restrict__ eids,
    const int* __restrict__ dtf) {
    int node = blockIdx.x * 4 + (threadIdx.x >> 6);
    if (node >= NN) return;
    int dt = dtf[0];
    int lane = threadIdx.x & 63;
    int half = lane >> 5;
    int j = lane & 31;
    int col = half * 192 + j * 6;

    float qv[6], we[6];
    {
        const u32* p = (const u32*)(qbuf + (size_t)node * 384 + col);
        #pragma unroll
        for (int t = 0; t < 3; t++) {
            u32 w = p[t];
            qv[2 * t] = bf2f(w & 0xffff); qv[2 * t + 1] = bf2f(w >> 16);
        }
        #pragma unroll
        for (int t = 0; t < 6; t++) we[t] = ldf(WE, col + t, dt);
    }
    int beg = indptr[node], end = indptr[node + 1];
    if (beg < 0) beg = 0; if (beg > NE) beg = NE;
    if (end < beg) end = beg; if (end > NE) end = NE;
    float m_run = -1e30f, l_run = 0.0f;
    float acc[6] = {0, 0, 0, 0, 0, 0};

    for (int it = beg; it < end; ++it) {
        int eid = eids[it];
        if ((u32)eid >= NE) eid = 0;
        int src = eidx[eid];                    // row 0 = src
        if ((u32)src >= NN) src = 0;
        float attr = ldf(eattr, eid, dt);
        const u32* kp = (const u32*)(kv + (size_t)src * 768 + col);
        const u32* vp = (const u32*)(kv + (size_t)src * 768 + 384 + col);
        float kj[6], vj[6];
        #pragma unroll
        for (int t = 0; t < 3; t++) {
            u32 wk = kp[t];
            kj[2 * t]     = bf2f(wk & 0xffff) + attr * we[2 * t];
            kj[2 * t + 1] = bf2f(wk >> 16)    + attr * we[2 * t + 1];
            u32 wv = vp[t];
            vj[2 * t]     = bf2f(wv & 0xffff) + attr * we[2 * t];
            vj[2 * t + 1] = bf2f(wv >> 16)    + attr * we[2 * t + 1];
        }
        float part = qv[0] * kj[0] + qv[1] * kj[1] + qv[2] * kj[2] +
                     qv[3] * kj[3] + qv[4] * kj[4] + qv[5] * kj[5];
        #pragma unroll
        for (int off = 1; off < 32; off <<= 1) part += __shfl_xor(part, off, 64);
        float s = part * 0.07216878364870323f;   // 1/sqrt(192)
        float mn = fmaxf(m_run, s);
        float corr = __expf(m_run - mn);
        float p = __expf(s - mn);
        l_run = l_run * corr + p;
        #pragma unroll
        for (int t = 0; t < 6; t++) acc[t] = acc[t] * corr + p * vj[t];
        m_run = mn;
    }
    float inv = (end > beg) ? 1.0f / (l_run + 1e-16f) : 0.0f;
    u16* ar = qbuf + (size_t)node * 384 + col;   // in-place over q row
    #pragma unroll
    for (int t = 0; t < 6; t++) ar[t] = f2bf(acc[t] * inv);
}

// ---------- LayerNorm: wave per row; bf16 preln in, output dtype per flag ----
__global__ __launch_bounds__(256) void ln_k(const u16* __restrict__ x,
                                            const void* __restrict__ g,
                                            const void* __restrict__ b,
                                            void* __restrict__ out,
                                            const int* __restrict__ dtf) {
    int node = blockIdx.x * 4 + (threadIdx.x >> 6);
    if (node >= NN) return;
    int dt = dtf[0];
    int lane = threadIdx.x & 63;
    const u32* row = (const u32*)(x + (size_t)node * 384 + lane * 6);
    float v[6];
    #pragma unroll
    for (int t = 0; t < 3; t++) {
        u32 w = row[t];
        v[2 * t] = bf2f(w & 0xffff); v[2 * t + 1] = bf2f(w >> 16);
    }
    float s = v[0] + v[1] + v[2] + v[3] + v[4] + v[5];
    #pragma unroll
    for (int off = 1; off < 64; off <<= 1) s += __shfl_xor(s, off, 64);
    float mean = s * (1.0f / 384.0f);
    float sq = 0.0f;
    #pragma unroll
    for (int t = 0; t < 6; t++) { float d = v[t] - mean; sq += d * d; }
    #pragma unroll
    for (int off = 1; off < 64; off <<= 1) sq += __shfl_xor(sq, off, 64);
    float rstd = rsqrtf(sq * (1.0f / 384.0f) + 1e-5f);
    size_t o0 = (size_t)node * 384 + lane * 6;
    #pragma unroll
    for (int t = 0; t < 6; t++) {
        float gv = ldf(g, lane * 6 + t, dt), bv = ldf(b, lane * 6 + t, dt);
        float val = (v[t] - mean) * rstd * gv + bv;
        if (dt) ((float*)out)[o0 + t] = val;
        else    ((u16*)out)[o0 + t] = f2bf(val);
    }
}

// ---------- launch ----------
extern "C" void kernel_launch(void* const* d_in, const int* in_sizes, int n_in,
                              void* d_out, int out_size, void* d_ws, size_t ws_size,
                              hipStream_t stream) {
    const void* emb   = d_in[0];
    const int*  eidx  = (const int*)d_in[1];
    const void* eattr = d_in[2];
    const void* WQ    = d_in[3];
    const void* WK    = d_in[4];
    const void* WV    = d_in[5];
    const void* WE    = d_in[6];
    const void* WO    = d_in[7];
    const void* lng   = d_in[8];
    const void* lnb   = d_in[9];

    char* ws = (char*)d_ws;
    // ws layout (79,180,800 B total — proven available in R4):
    //   ints+flag+eids+Wt (2.38 MB) | q/agg bf16 38.4 MB | preln bf16 38.4 MB
    // kv bf16 [NN][768] = 76.8 MB lives in d_out (dead until ln_k writes).
    const size_t OFF_IPTR = 0;           // (NN+1)*4 -> pad 200,064
    const size_t OFF_CNT  = 200064;      // NN*4 -> 400,064
    const size_t OFF_BSUM = 400064;      // 256*4 -> 401,088
    const size_t OFF_FLAG = 401088;      // 64 -> 401,152
    const size_t OFF_EIDS = 401152;      // NE*4 -> 1,201,152
    const size_t OFF_WT   = 1201152;     // 1536*384*2 -> 2,380,800
    const size_t OFF_Q    = 2380800;     // 50000*384*2 -> 40,780,800
    const size_t OFF_PRE  = 40780800;    // 50000*384*2 -> 79,180,800

    if (ws_size < 79180800) return;      // diagnostic guard

    int*   indptr = (int*)(ws + OFF_IPTR);
    int*   cnt    = (int*)(ws + OFF_CNT);
    int*   bsum   = (int*)(ws + OFF_BSUM);
    int*   dtf    = (int*)(ws + OFF_FLAG);
    int*   eids   = (int*)(ws + OFF_EIDS);
    u16*   Wt     = (u16*)(ws + OFF_WT);
    u16*   qa     = (u16*)(ws + OFF_Q);       // q -> agg (in-place)
    u16*   preln  = (u16*)(ws + OFF_PRE);
    u16*   kv     = (u16*)d_out;              // k|v, dead before final write

    const int NB_N = (NN + 255) / 256;   // 196
    const int NB_E = (NE + 255) / 256;   // 782

    detect_k<<<1, 256, 0, stream>>>((const u16*)emb, dtf);
    packw_k<<<(1536 * 384 + 255) / 256, 256, 0, stream>>>(WQ, WK, WV, WO, Wt, dtf);
    zero_k<<<NB_N, 256, 0, stream>>>(cnt, NN);
    hist_k<<<NB_E, 256, 0, stream>>>(eidx, cnt);
    scan1_k<<<NB_N, 256, 0, stream>>>(cnt, indptr, bsum);
    scan2_k<<<1, 256, 0, stream>>>(bsum, NB_N);
    scan3_k<<<NB_N, 256, 0, stream>>>(indptr, bsum, cnt);
    scatter_k<<<NB_E, 256, 0, stream>>>(eidx, indptr, cnt, eids);

    // fused q|k|v projection, n-fast grid: A fetched ~once via L2/L3 sharing
    gemm_k<0><<<dim3(9, 391), 256, 0, stream>>>(emb, Wt, qa, kv, nullptr,
                                                nullptr, dtf, NN);

    attn_k<<<(NN + 3) / 4, 256, 0, stream>>>(qa, kv, eidx, eattr, WE,
                                             indptr, eids, dtf);

    // output projection + residual -> bf16 preln
    gemm_k<1><<<dim3(3, 391), 256, 0, stream>>>(qa, Wt + 1152 * 384, nullptr,
                                                nullptr, preln, emb, dtf, NN);

    ln_k<<<(NN + 3) / 4, 256, 0, stream>>>(preln, lng, lnb, d_out, dtf);
}

// Round 7
// 458.358 us; speedup vs baseline: 1.1179x; 1.1039x over previous
//
#include <hip/hip_runtime.h>

#define NN 50000
#define NE 200000
#define DD 384

typedef unsigned short u16;
typedef unsigned int   u32;
typedef __attribute__((ext_vector_type(8))) __bf16 bf16x8;
typedef __attribute__((ext_vector_type(8))) short  short8;
typedef __attribute__((ext_vector_type(4))) float  f32x4;

// ---------- bf16 helpers (raw ushort storage) ----------
__device__ __forceinline__ float bf2f(u16 v) {
    union { u32 u; float f; } x; x.u = ((u32)v) << 16; return x.f;
}
__device__ __forceinline__ u16 f2bf(float f) {
    union { float f; u32 u; } x; x.f = f;
    u32 r = x.u + 0x7fff + ((x.u >> 16) & 1);   // RNE
    return (u16)(r >> 16);
}

// ---------- input dtype detector: flag=1 -> inputs are fp32 ----------
__global__ __launch_bounds__(256) void detect_k(const u16* __restrict__ p,
                                                int* __restrict__ flag) {
    __shared__ int tot;
    if (threadIdx.x == 0) tot = 0;
    __syncthreads();
    int bad = 0;
    for (int i = threadIdx.x; i < 8192; i += 256) {
        u16 v = p[i];
        int e = (v >> 7) & 0xFF;
        if (e >= 0x86) bad++;
    }
    atomicAdd(&tot, bad);
    __syncthreads();
    if (threadIdx.x == 0) flag[0] = (tot > 400) ? 1 : 0;
}

__device__ __forceinline__ float ldf(const void* p, size_t i, int dt) {
    return dt ? ((const float*)p)[i] : bf2f(((const u16*)p)[i]);
}

// ---------- cast embeddings -> bf16 once ----------
__global__ __launch_bounds__(256) void cast_k(const void* __restrict__ src,
                                              u16* __restrict__ dst,
                                              const int* __restrict__ dtf) {
    size_t i = ((size_t)blockIdx.x * 256 + threadIdx.x) * 8;
    if (i >= (size_t)NN * 384) return;
    if (dtf[0]) {
        const float* s = (const float*)src + i;
        f32x4 a0 = *(const f32x4*)s;
        f32x4 a1 = *(const f32x4*)(s + 4);
        short8 o;
        o[0] = (short)f2bf(a0[0]); o[1] = (short)f2bf(a0[1]);
        o[2] = (short)f2bf(a0[2]); o[3] = (short)f2bf(a0[3]);
        o[4] = (short)f2bf(a1[0]); o[5] = (short)f2bf(a1[1]);
        o[6] = (short)f2bf(a1[2]); o[7] = (short)f2bf(a1[3]);
        *(short8*)(dst + i) = o;
    } else {
        *(short8*)(dst + i) = *(const short8*)((const u16*)src + i);
    }
}

// ---------- weight pack: Wt[n][k] = W[k][n] bf16, n in [0,1536): Q|K|V|O ----
__global__ void packw_k(const void* __restrict__ WQ, const void* __restrict__ WK,
                        const void* __restrict__ WV, const void* __restrict__ WO,
                        u16* __restrict__ Wt, const int* __restrict__ dtf) {
    int idx = blockIdx.x * 256 + threadIdx.x;
    if (idx >= 1536 * 384) return;
    int dt = dtf[0];
    int n = idx / 384, k = idx - n * 384;
    const void* W; int c;
    if (n < 384)       { W = WQ; c = n; }
    else if (n < 768)  { W = WK; c = n - 384; }
    else if (n < 1152) { W = WV; c = n - 768; }
    else               { W = WO; c = n - 1152; }
    size_t off = (size_t)k * 384 + c;
    Wt[idx] = dt ? f2bf(((const float*)W)[off]) : ((const u16*)W)[off];
}

// ---------- CSR build ----------
__global__ void zero_k(int* p, int n) {
    int i = blockIdx.x * 256 + threadIdx.x;
    if (i < n) p[i] = 0;
}
__global__ void hist_k(const int* __restrict__ eidx, int* __restrict__ cnt) {
    int e = blockIdx.x * 256 + threadIdx.x;
    if (e < NE) {
        int d = eidx[NE + e];
        if ((u32)d < NN) atomicAdd(&cnt[d], 1);
    }
}
__global__ __launch_bounds__(256) void scan1_k(const int* __restrict__ cnt,
                                               int* __restrict__ indptr,
                                               int* __restrict__ bsum) {
    __shared__ int tmp[256];
    int i = blockIdx.x * 256 + threadIdx.x;
    int v = (i < NN) ? cnt[i] : 0;
    tmp[threadIdx.x] = v;
    __syncthreads();
    #pragma unroll
    for (int off = 1; off < 256; off <<= 1) {
        int t = tmp[threadIdx.x];
        int a = (threadIdx.x >= off) ? tmp[threadIdx.x - off] : 0;
        __syncthreads();
        tmp[threadIdx.x] = t + a;
        __syncthreads();
    }
    if (i < NN) indptr[i + 1] = tmp[threadIdx.x];
    if (threadIdx.x == 255) bsum[blockIdx.x] = tmp[255];
}
__global__ __launch_bounds__(256) void scan2_k(int* __restrict__ bsum, int nb) {
    __shared__ int tmp[256];
    int v = (threadIdx.x < nb) ? bsum[threadIdx.x] : 0;
    tmp[threadIdx.x] = v;
    __syncthreads();
    #pragma unroll
    for (int off = 1; off < 256; off <<= 1) {
        int t = tmp[threadIdx.x];
        int a = (threadIdx.x >= off) ? tmp[threadIdx.x - off] : 0;
        __syncthreads();
        tmp[threadIdx.x] = t + a;
        __syncthreads();
    }
    if (threadIdx.x < nb) bsum[threadIdx.x] = tmp[threadIdx.x] - v;  // exclusive
}
__global__ void scan3_k(int* __restrict__ indptr, const int* __restrict__ bsum,
                        int* __restrict__ cnt) {
    int i = blockIdx.x * 256 + threadIdx.x;
    if (i < NN) { indptr[i + 1] += bsum[blockIdx.x]; cnt[i] = 0; }
    if (i == 0) indptr[0] = 0;
}
__global__ void scatter_k(const int* __restrict__ eidx, const int* __restrict__ indptr,
                          int* __restrict__ cur, int* __restrict__ eids) {
    int e = blockIdx.x * 256 + threadIdx.x;
    if (e < NE) {
        int d = eidx[NE + e];
        if ((u32)d < NN) {
            int p = atomicAdd(&cur[d], 1);
            int slot = indptr[d] + p;
            if ((u32)slot < NE) eids[slot] = e;
        }
    }
}

// ---------- MFMA GEMM, XCD-swizzled 1-D grid ----------
// b&7 = XCD slot; the NT n-tiles of one m-tile land on the SAME XCD as
// 8-apart consecutive blocks -> A tile shared through that XCD's L2.
// 128x128 tile, 4 waves 2x2, 4x4 frags of 16x16x32 bf16. A always bf16.
// MODE 0 (QKV): n<384 -> q (ld 384), n>=384 -> kv (ld 768).
// MODE 1 (OUT): C = bf16 preln = acc + resid (fp32/bf16 per flag).
// NOTE: preln must NOT alias A — sibling n-tile blocks of the same m-tile
// read ALL 384 columns of the A rows this block writes (R6 race).
template <int MODE, int NT>
__global__ __launch_bounds__(256) void gemm_k(
    const u16* __restrict__ A, const u16* __restrict__ Bt,
    u16* __restrict__ qd, u16* __restrict__ kvd, u16* __restrict__ preln,
    const void* __restrict__ resid, const int* __restrict__ dtf, int M) {
    __shared__ __align__(16) short As[128 * 32];
    __shared__ __align__(16) short Bs[128 * 32];
    const int b    = blockIdx.x;
    const int xcd  = b & 7;
    const int j    = b >> 3;
    const int mg   = j / NT;
    const int nt   = j - mg * NT;
    const int m_idx = mg * 8 + xcd;
    if (m_idx >= (M + 127) / 128) return;
    const int m0 = m_idx * 128;
    const int n0 = nt * 128;
    const int tid  = threadIdx.x;
    const int lane = tid & 63;
    const int wave = tid >> 6;
    const int wm = (wave >> 1) * 64;
    const int wn = (wave & 1) * 64;
    const int q = lane >> 4;     // 0..3
    const int r = lane & 15;     // 0..15
    const int dt = (MODE == 1) ? dtf[0] : 0;

    f32x4 acc[4][4];
    #pragma unroll
    for (int i = 0; i < 4; i++)
        #pragma unroll
        for (int jj = 0; jj < 4; jj++) acc[i][jj] = (f32x4)(0.0f);

    const int srow = tid >> 2;          // 0..63
    const int scol = (tid & 3) * 8;     // element offset in 32-wide K block

    for (int kb = 0; kb < 12; ++kb) {
        const int k0 = kb * 32;
        #pragma unroll
        for (int h = 0; h < 2; ++h) {
            int row = h * 64 + srow;
            int am = m0 + row; am = am < M ? am : M - 1;
            *(short8*)&As[row * 32 + scol] =
                *(const short8*)(A + (size_t)am * 384 + k0 + scol);
            *(short8*)&Bs[row * 32 + scol] =
                *(const short8*)(Bt + (size_t)(n0 + row) * 384 + k0 + scol);
        }
        __syncthreads();
        bf16x8 af[4], bfr[4];
        #pragma unroll
        for (int i = 0; i < 4; i++)
            af[i] = *(const bf16x8*)&As[(wm + i * 16 + r) * 32 + q * 8];
        #pragma unroll
        for (int jj = 0; jj < 4; jj++)
            bfr[jj] = *(const bf16x8*)&Bs[(wn + jj * 16 + r) * 32 + q * 8];
        #pragma unroll
        for (int i = 0; i < 4; i++)
            #pragma unroll
            for (int jj = 0; jj < 4; jj++)
                acc[i][jj] = __builtin_amdgcn_mfma_f32_16x16x32_bf16(
                    af[i], bfr[jj], acc[i][jj], 0, 0, 0);
        __syncthreads();
    }

    // block-uniform destination routing
    u16* C; int ld, c0;
    if (MODE == 0) {
        if (n0 < 384) { C = qd;  ld = 384; c0 = n0; }
        else          { C = kvd; ld = 768; c0 = n0 - 384; }
    } else {
        C = preln; ld = 384; c0 = n0;
    }

    // D layout: col = lane&15, row = (lane>>4)*4 + reg   [measured m89/m91]
    #pragma unroll
    for (int i = 0; i < 4; i++) {
        #pragma unroll
        for (int rr = 0; rr < 4; ++rr) {
            int m = m0 + wm + i * 16 + q * 4 + rr;
            if (m >= M) continue;
            #pragma unroll
            for (int jj = 0; jj < 4; jj++) {
                int n = c0 + wn + jj * 16 + r;
                float v = acc[i][jj][rr];
                if (MODE == 1)
                    v += ldf(resid, (size_t)m * 384 + n, dt);
                C[(size_t)m * ld + n] = f2bf(v);
            }
        }
    }
}

// ---------- per-node attention ----------
// wave per node; lanes 0-31 = head0, 32-63 = head1; 6 elems/lane (192/32).
__global__ __launch_bounds__(256) void attn_k(
    u16* __restrict__ qbuf,              // [NN][384] bf16, becomes agg
    const u16* __restrict__ kv,          // [NN][768] bf16 = k|v
    const int* __restrict__ eidx,
    const void* __restrict__ eattr, const void* __restrict__ WE,
    const int* __restrict__ indptr, const int* __restrict__ eids,
    const int* __restrict__ dtf) {
    int node = blockIdx.x * 4 + (threadIdx.x >> 6);
    if (node >= NN) return;
    int dt = dtf[0];
    int lane = threadIdx.x & 63;
    int half = lane >> 5;
    int j = lane & 31;
    int col = half * 192 + j * 6;

    float qv[6], we[6];
    {
        const u32* p = (const u32*)(qbuf + (size_t)node * 384 + col);
        #pragma unroll
        for (int t = 0; t < 3; t++) {
            u32 w = p[t];
            qv[2 * t] = bf2f(w & 0xffff); qv[2 * t + 1] = bf2f(w >> 16);
        }
        #pragma unroll
        for (int t = 0; t < 6; t++) we[t] = ldf(WE, col + t, dt);
    }
    int beg = indptr[node], end = indptr[node + 1];
    if (beg < 0) beg = 0; if (beg > NE) beg = NE;
    if (end < beg) end = beg; if (end > NE) end = NE;
    float m_run = -1e30f, l_run = 0.0f;
    float acc[6] = {0, 0, 0, 0, 0, 0};

    for (int it = beg; it < end; ++it) {
        int eid = eids[it];
        if ((u32)eid >= NE) eid = 0;
        int src = eidx[eid];                    // row 0 = src
        if ((u32)src >= NN) src = 0;
        float attr = ldf(eattr, eid, dt);
        const u32* kp = (const u32*)(kv + (size_t)src * 768 + col);
        const u32* vp = (const u32*)(kv + (size_t)src * 768 + 384 + col);
        float kj[6], vj[6];
        #pragma unroll
        for (int t = 0; t < 3; t++) {
            u32 wk = kp[t];
            kj[2 * t]     = bf2f(wk & 0xffff) + attr * we[2 * t];
            kj[2 * t + 1] = bf2f(wk >> 16)    + attr * we[2 * t + 1];
            u32 wv = vp[t];
            vj[2 * t]     = bf2f(wv & 0xffff) + attr * we[2 * t];
            vj[2 * t + 1] = bf2f(wv >> 16)    + attr * we[2 * t + 1];
        }
        float part = qv[0] * kj[0] + qv[1] * kj[1] + qv[2] * kj[2] +
                     qv[3] * kj[3] + qv[4] * kj[4] + qv[5] * kj[5];
        #pragma unroll
        for (int off = 1; off < 32; off <<= 1) part += __shfl_xor(part, off, 64);
        float s = part * 0.07216878364870323f;   // 1/sqrt(192)
        float mn = fmaxf(m_run, s);
        float corr = __expf(m_run - mn);
        float p = __expf(s - mn);
        l_run = l_run * corr + p;
        #pragma unroll
        for (int t = 0; t < 6; t++) acc[t] = acc[t] * corr + p * vj[t];
        m_run = mn;
    }
    float inv = (end > beg) ? 1.0f / (l_run + 1e-16f) : 0.0f;
    u16* ar = qbuf + (size_t)node * 384 + col;   // in-place over q row
    #pragma unroll
    for (int t = 0; t < 6; t++) ar[t] = f2bf(acc[t] * inv);
}

// ---------- LayerNorm: wave per row; bf16 preln in, output dtype per flag ----
__global__ __launch_bounds__(256) void ln_k(const u16* __restrict__ x,
                                            const void* __restrict__ g,
                                            const void* __restrict__ b,
                                            void* __restrict__ out,
                                            const int* __restrict__ dtf) {
    int node = blockIdx.x * 4 + (threadIdx.x >> 6);
    if (node >= NN) return;
    int dt = dtf[0];
    int lane = threadIdx.x & 63;
    const u32* row = (const u32*)(x + (size_t)node * 384 + lane * 6);
    float v[6];
    #pragma unroll
    for (int t = 0; t < 3; t++) {
        u32 w = row[t];
        v[2 * t] = bf2f(w & 0xffff); v[2 * t + 1] = bf2f(w >> 16);
    }
    float s = v[0] + v[1] + v[2] + v[3] + v[4] + v[5];
    #pragma unroll
    for (int off = 1; off < 64; off <<= 1) s += __shfl_xor(s, off, 64);
    float mean = s * (1.0f / 384.0f);
    float sq = 0.0f;
    #pragma unroll
    for (int t = 0; t < 6; t++) { float d = v[t] - mean; sq += d * d; }
    #pragma unroll
    for (int off = 1; off < 64; off <<= 1) sq += __shfl_xor(sq, off, 64);
    float rstd = rsqrtf(sq * (1.0f / 384.0f) + 1e-5f);
    size_t o0 = (size_t)node * 384 + lane * 6;
    #pragma unroll
    for (int t = 0; t < 6; t++) {
        float gv = ldf(g, lane * 6 + t, dt), bv = ldf(b, lane * 6 + t, dt);
        float val = (v[t] - mean) * rstd * gv + bv;
        if (dt) ((float*)out)[o0 + t] = val;
        else    ((u16*)out)[o0 + t] = f2bf(val);
    }
}

// ---------- launch ----------
extern "C" void kernel_launch(void* const* d_in, const int* in_sizes, int n_in,
                              void* d_out, int out_size, void* d_ws, size_t ws_size,
                              hipStream_t stream) {
    const void* emb   = d_in[0];
    const int*  eidx  = (const int*)d_in[1];
    const void* eattr = d_in[2];
    const void* WQ    = d_in[3];
    const void* WK    = d_in[4];
    const void* WV    = d_in[5];
    const void* WE    = d_in[6];
    const void* WO    = d_in[7];
    const void* lng   = d_in[8];
    const void* lnb   = d_in[9];

    char* ws = (char*)d_ws;
    // ws layout — exactly 79,180,800 B (proven available in R4/R5):
    //   ints+flag+eids+Wt (2.38 MB) | ebf 38.4 MB | q/agg 38.4 MB
    // kv bf16 [NN][768] = 76.8 MB lives in d_out (dead until ln_k writes).
    // preln reuses the EBF region (dead after QKV GEMM) — never aliases A.
    const size_t OFF_IPTR = 0;           // (NN+1)*4 -> pad 200,064
    const size_t OFF_CNT  = 200064;      // NN*4 -> 400,064
    const size_t OFF_BSUM = 400064;      // 256*4 -> 401,088
    const size_t OFF_FLAG = 401088;      // 64 -> 401,152
    const size_t OFF_EIDS = 401152;      // NE*4 -> 1,201,152
    const size_t OFF_WT   = 1201152;     // 1536*384*2 -> 2,380,800
    const size_t OFF_EBF  = 2380800;     // 50000*384*2 -> 40,780,800
    const size_t OFF_Q    = 40780800;    // 50000*384*2 -> 79,180,800

    if (ws_size < 79180800) return;      // diagnostic guard

    int*   indptr = (int*)(ws + OFF_IPTR);
    int*   cnt    = (int*)(ws + OFF_CNT);
    int*   bsum   = (int*)(ws + OFF_BSUM);
    int*   dtf    = (int*)(ws + OFF_FLAG);
    int*   eids   = (int*)(ws + OFF_EIDS);
    u16*   Wt     = (u16*)(ws + OFF_WT);
    u16*   ebf    = (u16*)(ws + OFF_EBF);     // bf16 embeddings, then preln
    u16*   qa     = (u16*)(ws + OFF_Q);       // q -> agg (in-place)
    u16*   preln  = ebf;                      // ebf dead after QKV GEMM
    u16*   kv     = (u16*)d_out;              // k|v, dead before final write

    const int NB_N = (NN + 255) / 256;   // 196
    const int NB_E = (NE + 255) / 256;   // 782

    detect_k<<<1, 256, 0, stream>>>((const u16*)emb, dtf);
    cast_k<<<(NN * 384 / 8 + 255) / 256, 256, 0, stream>>>(emb, ebf, dtf);
    packw_k<<<(1536 * 384 + 255) / 256, 256, 0, stream>>>(WQ, WK, WV, WO, Wt, dtf);
    zero_k<<<NB_N, 256, 0, stream>>>(cnt, NN);
    hist_k<<<NB_E, 256, 0, stream>>>(eidx, cnt);
    scan1_k<<<NB_N, 256, 0, stream>>>(cnt, indptr, bsum);
    scan2_k<<<1, 256, 0, stream>>>(bsum, NB_N);
    scan3_k<<<NB_N, 256, 0, stream>>>(indptr, bsum, cnt);
    scatter_k<<<NB_E, 256, 0, stream>>>(eidx, indptr, cnt, eids);

    // fused q|k|v projection, XCD-swizzled: 392 m-slots x 9 n-tiles
    gemm_k<0, 9><<<392 * 9, 256, 0, stream>>>(ebf, Wt, qa, kv, nullptr,
                                              nullptr, dtf, NN);

    attn_k<<<(NN + 3) / 4, 256, 0, stream>>>(qa, kv, eidx, eattr, WE,
                                             indptr, eids, dtf);

    // output projection + residual -> preln (ebf region, disjoint from qa)
    gemm_k<1, 3><<<392 * 3, 256, 0, stream>>>(qa, Wt + 1152 * 384, nullptr,
                                              nullptr, preln, emb, dtf, NN);

    ln_k<<<(NN + 3) / 4, 256, 0, stream>>>(preln, lng, lnb, d_out, dtf);
}